// Round 1
// baseline (15199.994 us; speedup 1.0000x reference)
//
#include <hip/hip_runtime.h>
#include <hip/hip_cooperative_groups.h>
#include <math.h>

namespace cg = cooperative_groups;

#define Bn 512
#define Tn 256
#define Hn 512
#define Vn 7
#define BH (Bn*Hn)          // 262144
#define NLP (Bn*Tn*Vn)      // 917504

__device__ __forceinline__ float sigf(float x){ return 1.0f/(1.0f + expf(-x)); }

// grid 256 blocks x 512 threads. block tile: 32 b x 32 j x 4 gates.
// threads split in two halves over K (each half K=256, staged in 8 chunks of 32).
extern "C" __global__ void __launch_bounds__(512, 2)
decoder_rnn_kernel(const float* __restrict__ h0, const float* __restrict__ c0,
                   const float* __restrict__ tgt, const float* __restrict__ Wih,
                   const float* __restrict__ Whh, const float* __restrict__ bih,
                   const float* __restrict__ bhh, const float* __restrict__ Wout,
                   const float* __restrict__ bout, float* out, float* ws)
{
    cg::grid_group grid = cg::this_grid();

    float* hbuf = ws;            // 2*BH floats (ping-pong h)
    float* cws  = ws + 2*BH;     // BH floats (c, in-place per owner)
    float* lp   = out;           // NLP floats: raw logits during loop, logp at end

    // stride 36 floats = 144B: 16B-aligned rows, row*9 mod 8 spreads bank groups
    __shared__ float A_lds[2][32*36];
    __shared__ float W_lds[2][128*36];
    __shared__ float hn_lds[32*33];
    __shared__ int   idx_lds[32];

    const int bt = blockIdx.x >> 4;   // 16 b-tiles
    const int jt = blockIdx.x & 15;   // 16 j-tiles
    const int b0 = bt << 5;
    const int j0 = jt << 5;
    const int hf  = threadIdx.x >> 8;     // K-half 0/1
    const int tid = threadIdx.x & 255;
    const int tb  = tid & 7;              // b-group: b_local = tb + 8*bi
    const int tn  = tid >> 3;             // j within tile (0..31)

    const int gtid = blockIdx.x*512 + threadIdx.x;   // 0..131071 == B*T
    const int nthr = 256*512;

    // ---- init: zero logits region, load h0/c0 into workspace ----
    for (int i = gtid; i < NLP; i += nthr) lp[i] = 0.0f;
    for (int i = gtid; i < BH; i += nthr){ hbuf[i] = h0[i]; cws[i] = c0[i]; }
    grid.sync();

    for (int t = 0; t < Tn; ++t){
        const float* hprev = hbuf + (t & 1)*BH;
        float*       hnext = hbuf + ((t + 1) & 1)*BH;

        // ---- phase 1: per-b argmax -> one-hot index (x is always one-hot; relu no-op) ----
        if (threadIdx.x < 32){
            const int  bl = threadIdx.x;
            const long b  = b0 + bl;
            float best; int am = 0;
            if (t == 0){
                const float* xp = tgt + (b*Tn)*Vn;       // target_onehot[b,0,:]
                best = xp[0];
                #pragma unroll
                for (int v = 1; v < Vn; ++v){ float xv = xp[v]; if (xv > best){ best = xv; am = v; } }
            } else {
                const float* xp = lp + (b*Tn + (t-1))*Vn;
                best = xp[0] + bout[0];
                #pragma unroll
                for (int v = 1; v < Vn; ++v){ float xv = xp[v] + bout[v]; if (xv > best){ best = xv; am = v; } }
            }
            idx_lds[bl] = am;
        }

        // ---- GEMM: gates[b, gi*512 + j] over this half's K range ----
        float acc[4][4];
        #pragma unroll
        for (int a = 0; a < 4; ++a)
            #pragma unroll
            for (int g = 0; g < 4; ++g) acc[a][g] = 0.0f;

        for (int c = 0; c < 8; ++c){
            const int k0 = hf*256 + c*32;
            {   // stage A (32 b x 32 k) and W (128 rows x 32 k), coalesced
                const int k  = tid & 31;
                const int rr = tid >> 5;   // 0..7
                #pragma unroll
                for (int r = rr; r < 32; r += 8)
                    A_lds[hf][r*36 + k] = hprev[(long)(b0 + r)*Hn + k0 + k];
                #pragma unroll
                for (int r = rr; r < 128; r += 8){
                    const int gi = r >> 5, jj = r & 31;
                    W_lds[hf][r*36 + k] = Whh[(long)((gi<<9) + j0 + jj)*Hn + k0 + k];
                }
            }
            __syncthreads();
            #pragma unroll 2
            for (int k = 0; k < 32; k += 4){
                float4 av[4], wv[4];
                #pragma unroll
                for (int i = 0; i < 4; ++i)
                    av[i] = *reinterpret_cast<const float4*>(&A_lds[hf][(tb + 8*i)*36 + k]);
                #pragma unroll
                for (int i = 0; i < 4; ++i)
                    wv[i] = *reinterpret_cast<const float4*>(&W_lds[hf][((i<<5) + tn)*36 + k]);
                #pragma unroll
                for (int bi = 0; bi < 4; ++bi)
                    #pragma unroll
                    for (int gi = 0; gi < 4; ++gi){
                        float s = acc[bi][gi];
                        s = fmaf(av[bi].x, wv[gi].x, s);
                        s = fmaf(av[bi].y, wv[gi].y, s);
                        s = fmaf(av[bi].z, wv[gi].z, s);
                        s = fmaf(av[bi].w, wv[gi].w, s);
                        acc[bi][gi] = s;
                    }
            }
            __syncthreads();
        }

        // ---- reduce the two K-halves (half1 -> LDS, half0 adds) ----
        float* red = &W_lds[0][0];   // GEMM done; reuse. stride 20 -> conflict-free float4
        if (hf == 1){
            #pragma unroll
            for (int bi = 0; bi < 4; ++bi)
                *reinterpret_cast<float4*>(&red[tid*20 + bi*4]) =
                    make_float4(acc[bi][0], acc[bi][1], acc[bi][2], acc[bi][3]);
        }
        __syncthreads();

        // ---- epilogue: bias + W_ih column gather + LSTM cell (half0 only) ----
        if (hf == 0){
            #pragma unroll
            for (int bi = 0; bi < 4; ++bi){
                float4 r4 = *reinterpret_cast<const float4*>(&red[tid*20 + bi*4]);
                const int bl = tb + 8*bi;
                const long b = b0 + bl;
                const int j  = j0 + tn;
                const int ix = idx_lds[bl];
                float g4[4] = { acc[bi][0] + r4.x, acc[bi][1] + r4.y,
                                acc[bi][2] + r4.z, acc[bi][3] + r4.w };
                #pragma unroll
                for (int gi = 0; gi < 4; ++gi){
                    const int r = (gi<<9) + j;
                    g4[gi] += Wih[r*Vn + ix] + bih[r] + bhh[r];
                }
                const float iv = sigf(g4[0]);
                const float fv = sigf(g4[1]);
                const float gv = tanhf(g4[2]);
                const float ov = sigf(g4[3]);
                const float cold = cws[b*Hn + j];
                const float cn = fv*cold + iv*gv;
                cws[b*Hn + j] = cn;
                const float hn = ov * tanhf(cn);
                hnext[b*Hn + j] = hn;
                hn_lds[bl*33 + tn] = hn;
            }
        }
        __syncthreads();

        // ---- partial logits: out[b,v] += sum_j hn[b,j]*W_out[v,j] over our 32 j ----
        if (threadIdx.x < 224){
            const int bl = threadIdx.x / 7;
            const int v  = threadIdx.x % 7;
            const float* wo = Wout + v*Hn + j0;
            float s = 0.0f;
            #pragma unroll
            for (int jj = 0; jj < 32; ++jj)
                s = fmaf(hn_lds[bl*33 + jj], wo[jj], s);
            atomicAdd(&lp[((long)(b0 + bl)*Tn + t)*Vn + v], s);
        }

        grid.sync();   // includes device-scope fence: h ping-pong + logits visible
    }

    // ---- final: hT, cT, in-place log_softmax over V ----
    for (int i = gtid; i < BH; i += nthr){
        out[NLP + i]      = hbuf[i];   // T=256 even -> final h in buffer 0
        out[NLP + BH + i] = cws[i];
    }
    {
        const long row = gtid;         // exactly B*T rows
        float x[Vn]; float m = -INFINITY;
        #pragma unroll
        for (int v = 0; v < Vn; ++v){ x[v] = lp[row*Vn + v] + bout[v]; m = fmaxf(m, x[v]); }
        float s = 0.0f;
        #pragma unroll
        for (int v = 0; v < Vn; ++v) s += expf(x[v] - m);
        const float ls = logf(s);
        #pragma unroll
        for (int v = 0; v < Vn; ++v) lp[row*Vn + v] = x[v] - m - ls;
    }
}

extern "C" void kernel_launch(void* const* d_in, const int* in_sizes, int n_in,
                              void* d_out, int out_size, void* d_ws, size_t ws_size,
                              hipStream_t stream) {
    const float* h0   = (const float*)d_in[0];
    const float* c0   = (const float*)d_in[1];
    const float* tgt  = (const float*)d_in[2];
    const float* Wih  = (const float*)d_in[3];
    const float* Whh  = (const float*)d_in[4];
    const float* bih  = (const float*)d_in[5];
    const float* bhh  = (const float*)d_in[6];
    const float* Wout = (const float*)d_in[7];
    const float* bout = (const float*)d_in[8];
    float* out = (float*)d_out;
    float* ws  = (float*)d_ws;   // needs 3*BH floats = 3 MB

    void* args[] = { &h0, &c0, &tgt, &Wih, &Whh, &bih, &bhh, &Wout, &bout, &out, &ws };
    hipLaunchCooperativeKernel((const void*)decoder_rnn_kernel,
                               dim3(256), dim3(512), args, 0, stream);
}

// Round 5
// 10911.578 us; speedup vs baseline: 1.3930x; 1.3930x over previous
//
#include <hip/hip_runtime.h>
#include <math.h>

#define Bn 512
#define Tn 256
#define Hn 512
#define Vn 7
#define BH (Bn*Hn)          // 262144
#define NLP (Bn*Tn*Vn)      // 917504

#define NBLK 256
#define NTHR 512

// ARITHMETIC IS FROZEN to the round-1 kernel (the only order that passed):
// sequential k per half, half-add via LDS, epilogue expression order,
// 16x32 logit partition, libm expf/tanhf/logf. Do NOT reorder any sums.

__device__ __forceinline__ float sigf(float x){ return 1.0f/(1.0f + expf(-x)); }

__device__ __forceinline__ void grid_barrier(int* cnt, int target){
    __syncthreads();   // drains vmem stores per __syncthreads semantics
    if (threadIdx.x == 0){
        __hip_atomic_fetch_add(cnt, 1, __ATOMIC_RELEASE, __HIP_MEMORY_SCOPE_AGENT);
        // acquire-ordered spin: the load observing cnt>=target orders all later
        // reads after every block's release-increment (and invalidates L1)
        while (__hip_atomic_load(cnt, __ATOMIC_ACQUIRE, __HIP_MEMORY_SCOPE_AGENT) < target)
            __builtin_amdgcn_s_sleep(2);
    }
    __syncthreads();
}

__global__ void init_kernel(float* lp, int* cnt){
    int i = blockIdx.x*blockDim.x + threadIdx.x;
    if (i == 0) *cnt = 0;
    for (int x = i; x < NLP; x += (int)(gridDim.x*blockDim.x)) lp[x] = 0.0f;
}

// grid 256 x 512. block tile: 32 b x 32 j x 4 gates (round-1 tiling).
// two 256-thread K-halves; per chunk: float4 reg-prefetch -> LDS -> compute.
__global__ void __launch_bounds__(NTHR, 2)
decoder_rnn_kernel(const float* __restrict__ h0, const float* __restrict__ c0,
                   const float* __restrict__ tgt, const float* __restrict__ Wih,
                   const float* __restrict__ Whh, const float* __restrict__ bih,
                   const float* __restrict__ bhh, const float* __restrict__ Wout,
                   const float* __restrict__ bout, float* out, float* ws)
{
    __shared__ float A_lds[2][32*36];
    __shared__ float W_lds[2][128*36];
    __shared__ float hn_lds[32*33];
    __shared__ int   idx_lds[32];

    float* hbuf = ws;                 // 2*BH ping-pong h
    float* cws  = ws + 2*BH;          // BH c-state
    int*   cnt  = (int*)(ws + 3*BH);  // barrier counter (zeroed by init_kernel)
    float* lp   = out;                // logits -> logp in place

    const int bt = blockIdx.x >> 4;   // 16 b-tiles
    const int jt = blockIdx.x & 15;   // 16 j-tiles
    const int b0 = bt << 5;
    const int j0 = jt << 5;
    const int hf  = threadIdx.x >> 8;     // K-half 0/1
    const int tid = threadIdx.x & 255;
    const int tb  = tid & 7;              // b_local = tb + 8*bi
    const int tn  = tid >> 3;             // j within tile (0..31)

    const int gtid = blockIdx.x*NTHR + threadIdx.x;
    const int nthr = NBLK*NTHR;

    // ---- per-block state init (no grid barrier needed):
    // h rows b0..b0+31, full K (redundant across the 16 jt-blocks sharing bt —
    // identical values, benign); c patch (b0..b0+31, j0..j0+31) owned uniquely.
    #pragma unroll
    for (int i = 0; i < 8; ++i){
        const int f = threadIdx.x + (i << 9);
        const int r = f >> 7, c4 = f & 127;
        *(float4*)(hbuf + (long)(b0 + r)*Hn + (c4 << 2)) =
            *(const float4*)(h0 + (long)(b0 + r)*Hn + (c4 << 2));
    }
    if (threadIdx.x < 256){
        const int r = threadIdx.x >> 3, c4 = threadIdx.x & 7;
        *(float4*)(cws + (long)(b0 + r)*Hn + j0 + (c4 << 2)) =
            *(const float4*)(c0 + (long)(b0 + r)*Hn + j0 + (c4 << 2));
    }
    __syncthreads();

    for (int t = 0; t < Tn; ++t){
        const float* hprev = hbuf + (t & 1)*BH;
        float*       hnext = hbuf + ((t + 1) & 1)*BH;

        // ---- argmax -> one-hot index (verbatim round 1) ----
        if (threadIdx.x < 32){
            const int  bl = threadIdx.x;
            const long b  = b0 + bl;
            float best; int am = 0;
            if (t == 0){
                const float* xp = tgt + (b*Tn)*Vn;
                best = xp[0];
                #pragma unroll
                for (int v = 1; v < Vn; ++v){ float xv = xp[v]; if (xv > best){ best = xv; am = v; } }
            } else {
                const float* xp = lp + (b*Tn + (t-1))*Vn;
                best = xp[0] + bout[0];
                #pragma unroll
                for (int v = 1; v < Vn; ++v){ float xv = xp[v] + bout[v]; if (xv > best){ best = xv; am = v; } }
            }
            idx_lds[bl] = am;
        }

        float acc[4][4];
        #pragma unroll
        for (int a = 0; a < 4; ++a)
            #pragma unroll
            for (int g = 0; g < 4; ++g) acc[a][g] = 0.0f;

        // ---- prefetch chunk 0 into regs ----
        float4 wreg[4], areg;
        {
            const int k0 = hf << 8;
            #pragma unroll
            for (int i = 0; i < 4; ++i){
                const int f = tid + (i << 8);
                const int r = f >> 3, c4 = f & 7;
                const int gi = r >> 5, jj = r & 31;
                wreg[i] = *(const float4*)(Whh + (long)((gi<<9) + j0 + jj)*Hn + k0 + (c4 << 2));
            }
            areg = *(const float4*)(hprev + (long)(b0 + (tid >> 3))*Hn + k0 + ((tid & 7) << 2));
        }

        for (int c = 0; c < 8; ++c){
            __syncthreads();   // previous compute / epilogue LDS reads complete
            #pragma unroll
            for (int i = 0; i < 4; ++i){
                const int f = tid + (i << 8);
                const int r = f >> 3, c4 = f & 7;
                *(float4*)(&W_lds[hf][r*36 + (c4 << 2)]) = wreg[i];
            }
            *(float4*)(&A_lds[hf][(tid >> 3)*36 + ((tid & 7) << 2)]) = areg;
            __syncthreads();   // staging visible
            if (c < 7){        // prefetch next chunk; latency hidden by compute
                const int k0 = (hf << 8) + ((c + 1) << 5);
                #pragma unroll
                for (int i = 0; i < 4; ++i){
                    const int f = tid + (i << 8);
                    const int r = f >> 3, c4 = f & 7;
                    const int gi = r >> 5, jj = r & 31;
                    wreg[i] = *(const float4*)(Whh + (long)((gi<<9) + j0 + jj)*Hn + k0 + (c4 << 2));
                }
                areg = *(const float4*)(hprev + (long)(b0 + (tid >> 3))*Hn + k0 + ((tid & 7) << 2));
            }
            // ---- compute chunk c (verbatim round 1: sequential k, xyzw) ----
            #pragma unroll 2
            for (int k = 0; k < 32; k += 4){
                float4 av[4], wv[4];
                #pragma unroll
                for (int i = 0; i < 4; ++i)
                    av[i] = *reinterpret_cast<const float4*>(&A_lds[hf][(tb + 8*i)*36 + k]);
                #pragma unroll
                for (int i = 0; i < 4; ++i)
                    wv[i] = *reinterpret_cast<const float4*>(&W_lds[hf][((i<<5) + tn)*36 + k]);
                #pragma unroll
                for (int bi = 0; bi < 4; ++bi)
                    #pragma unroll
                    for (int gi = 0; gi < 4; ++gi){
                        float s = acc[bi][gi];
                        s = fmaf(av[bi].x, wv[gi].x, s);
                        s = fmaf(av[bi].y, wv[gi].y, s);
                        s = fmaf(av[bi].z, wv[gi].z, s);
                        s = fmaf(av[bi].w, wv[gi].w, s);
                        acc[bi][gi] = s;
                    }
            }
        }

        // ---- reduce the two K-halves (verbatim round 1) ----
        float* red = &W_lds[0][0];   // GEMM done; reuse. stride 20 float4-safe
        if (hf == 1){
            #pragma unroll
            for (int bi = 0; bi < 4; ++bi)
                *reinterpret_cast<float4*>(&red[tid*20 + bi*4]) =
                    make_float4(acc[bi][0], acc[bi][1], acc[bi][2], acc[bi][3]);
        }
        __syncthreads();

        // ---- epilogue (verbatim round 1) ----
        if (hf == 0){
            #pragma unroll
            for (int bi = 0; bi < 4; ++bi){
                float4 r4 = *reinterpret_cast<const float4*>(&red[tid*20 + bi*4]);
                const int bl = tb + 8*bi;
                const long b = b0 + bl;
                const int j  = j0 + tn;
                const int ix = idx_lds[bl];
                float g4[4] = { acc[bi][0] + r4.x, acc[bi][1] + r4.y,
                                acc[bi][2] + r4.z, acc[bi][3] + r4.w };
                #pragma unroll
                for (int gi = 0; gi < 4; ++gi){
                    const int r = (gi<<9) + j;
                    g4[gi] += Wih[r*Vn + ix] + bih[r] + bhh[r];
                }
                const float iv = sigf(g4[0]);
                const float fv = sigf(g4[1]);
                const float gv = tanhf(g4[2]);
                const float ov = sigf(g4[3]);
                const float cold = cws[b*Hn + j];
                const float cn = fv*cold + iv*gv;
                cws[b*Hn + j] = cn;
                const float hn = ov * tanhf(cn);
                hnext[b*Hn + j] = hn;
                hn_lds[bl*33 + tn] = hn;
            }
        }
        __syncthreads();

        // ---- partial logits, 16x32 partition (verbatim round 1) ----
        if (threadIdx.x < 224){
            const int bl = threadIdx.x / 7;
            const int v  = threadIdx.x % 7;
            const float* wo = Wout + v*Hn + j0;
            float s = 0.0f;
            #pragma unroll
            for (int jj = 0; jj < 32; ++jj)
                s = fmaf(hn_lds[bl*33 + jj], wo[jj], s);
            atomicAdd(&lp[((long)(b0 + bl)*Tn + t)*Vn + v], s);
        }

        grid_barrier(cnt, NBLK*(t+1));
    }

    // ---- final: hT, cT, in-place log_softmax (verbatim round 1) ----
    for (int i = gtid; i < BH; i += nthr){
        out[NLP + i]      = hbuf[i];   // T=256 even -> final h in buffer 0
        out[NLP + BH + i] = cws[i];
    }
    {
        const long row = gtid;         // exactly B*T rows
        float x[Vn]; float m = -INFINITY;
        #pragma unroll
        for (int v = 0; v < Vn; ++v){ x[v] = lp[row*Vn + v] + bout[v]; m = fmaxf(m, x[v]); }
        float s = 0.0f;
        #pragma unroll
        for (int v = 0; v < Vn; ++v) s += expf(x[v] - m);
        const float ls = logf(s);
        #pragma unroll
        for (int v = 0; v < Vn; ++v) lp[row*Vn + v] = x[v] - m - ls;
    }
}

extern "C" void kernel_launch(void* const* d_in, const int* in_sizes, int n_in,
                              void* d_out, int out_size, void* d_ws, size_t ws_size,
                              hipStream_t stream) {
    const float* h0   = (const float*)d_in[0];
    const float* c0   = (const float*)d_in[1];
    const float* tgt  = (const float*)d_in[2];
    const float* Wih  = (const float*)d_in[3];
    const float* Whh  = (const float*)d_in[4];
    const float* bih  = (const float*)d_in[5];
    const float* bhh  = (const float*)d_in[6];
    const float* Wout = (const float*)d_in[7];
    const float* bout = (const float*)d_in[8];
    float* out = (float*)d_out;
    float* ws  = (float*)d_ws;               // 3*BH floats + counter
    int*   cnt = (int*)(ws + 3*BH);

    init_kernel<<<256, 256, 0, stream>>>(out, cnt);

    void* args[] = { &h0, &c0, &tgt, &Wih, &Whh, &bih, &bhh, &Wout, &bout, &out, &ws };
    (void)hipLaunchCooperativeKernel((const void*)decoder_rnn_kernel,
                               dim3(NBLK), dim3(NTHR), args, 0, stream);
}